// Round 2
// baseline (173.238 us; speedup 1.0000x reference)
//
#include <hip/hip_runtime.h>
#include <math.h>

#define EPS 1e-5f
#define B 64
#define N 1024
#define W 64
#define R 4
#define NW 1
#define RPB 8   // rows per block in k_link

typedef float f4 __attribute__((ext_vector_type(4)));

__device__ __forceinline__ float softplus_f(float x) {
    return x > 0.f ? x + log1pf(expf(-x)) : log1pf(expf(x));
}

// Block-wide reduction over 1024 threads (16 waves). sred must hold 16 floats.
template <bool IS_MAX>
__device__ __forceinline__ float block_reduce(float v, float* sred) {
    #pragma unroll
    for (int off = 32; off >= 1; off >>= 1) {
        float o = __shfl_xor(v, off);
        v = IS_MAX ? fmaxf(v, o) : v + o;
    }
    int wid = threadIdx.x >> 6, lane = threadIdx.x & 63;
    __syncthreads();               // protect sred reuse across calls
    if (lane == 0) sred[wid] = v;
    __syncthreads();
    float r = sred[0];
    #pragma unroll
    for (int i = 1; i < 16; ++i) r = IS_MAX ? fmaxf(r, sred[i]) : r + sred[i];
    return r;
}

// ---- everything except the link update, fused: one block per batch ----
__global__ __launch_bounds__(1024) void k_small(
    const float* __restrict__ memory,
    const float* __restrict__ read_keys,
    const float* __restrict__ read_strengths,
    const float* __restrict__ write_keys,
    const float* __restrict__ write_strengths,
    const float* __restrict__ free_gate,
    const float* __restrict__ alloc_gate,
    const float* __restrict__ write_gate,
    const float* __restrict__ prev_read_w,
    const float* __restrict__ prev_write_w,
    const float* __restrict__ prev_usage,
    const float* __restrict__ prev_prec,
    float* __restrict__ out_rw,
    float* __restrict__ out_ww,
    float* __restrict__ out_usage,
    float* __restrict__ out_prec) {

    __shared__ float nu[N];
    __shared__ int   id[N];
    __shared__ float pp[N];
    __shared__ float salloc[N];
    __shared__ float sk[5 * W];
    __shared__ float sknorm[5];
    __shared__ float sscale[5];
    __shared__ float sred[16];

    int b = blockIdx.x;
    int t = threadIdx.x;   // == n index, 0..1023

    // keys to shared (covered by the first __syncthreads below)
    if (t < 5 * W) {
        int h = t >> 6, w = t & 63;
        sk[t] = (h < R) ? read_keys[((size_t)b * R + h) * W + w]
                        : write_keys[(size_t)b * W + w];
    }

    // ---- usage ---- (NW=1: ww = prev_write_w)
    float pwwv = prev_write_w[(size_t)b * N + t];
    float pun  = prev_usage[(size_t)b * N + t];
    float u = pun + (1.f - pun) * pwwv;
    float phi = 1.f;
    #pragma unroll
    for (int r = 0; r < R; ++r)
        phi *= 1.f - free_gate[b * R + r] * prev_read_w[((size_t)b * R + r) * N + t];
    float usage = u * phi;
    out_usage[(size_t)b * N + t] = usage;

    // ---- allocation: bitonic sort (desc nonusage, stable by index) ----
    float uu = EPS + (1.f - EPS) * usage;
    nu[t] = 1.f - uu;
    id[t] = t;
    __syncthreads();

    if (t < 5) {   // key norms + sharpening scales (sk is ready)
        float s = 0.f;
        for (int w = 0; w < W; ++w) s += sk[t * W + w] * sk[t * W + w];
        sknorm[t] = sqrtf(s + EPS);
        float st = (t < R) ? read_strengths[b * R + t] : write_strengths[b];
        sscale[t] = softplus_f(st);
    }

    for (int k = 2; k <= N; k <<= 1) {
        for (int j = k >> 1; j > 0; j >>= 1) {
            int ixj = t ^ j;
            if (ixj > t) {
                float na = nu[t], nb = nu[ixj];
                int   ia = id[t], ib = id[ixj];
                bool a_first = (na > nb) || (na == nb && ia < ib);
                bool up = ((t & k) == 0);
                bool doSwap = up ? !a_first : a_first;
                if (doSwap) {
                    nu[t] = nb; nu[ixj] = na;
                    id[t] = ib; id[ixj] = ia;
                }
            }
            __syncthreads();
        }
    }

    // inclusive prefix product of sorted_usage = 1 - nu
    pp[t] = 1.f - nu[t];
    __syncthreads();
    for (int off = 1; off < N; off <<= 1) {
        float v = pp[t];
        float w = (t >= off) ? pp[t - off] : 1.f;
        __syncthreads();
        pp[t] = v * w;
        __syncthreads();
    }
    float excl = (t > 0) ? pp[t - 1] : 1.f;
    salloc[id[t]] = nu[t] * excl;     // scatter through sort permutation

    // ---- cosine scores: thread t owns memory row t ----
    const f4* mrow = (const f4*)(memory + ((size_t)b * N + t) * W);
    float dot[5] = {0.f, 0.f, 0.f, 0.f, 0.f};
    float msum = 0.f;
    #pragma unroll
    for (int w4 = 0; w4 < W / 4; ++w4) {
        f4 m = mrow[w4];
        msum += m.x * m.x + m.y * m.y + m.z * m.z + m.w * m.w;
        #pragma unroll
        for (int h = 0; h < 5; ++h)
            dot[h] += sk[h * W + w4 * 4 + 0] * m.x + sk[h * W + w4 * 4 + 1] * m.y
                    + sk[h * W + w4 * 4 + 2] * m.z + sk[h * W + w4 * 4 + 3] * m.w;
    }
    __syncthreads();   // salloc scatter complete; sknorm/sscale ready
    float mnorm = sqrtf(msum + EPS);

    // ---- softmax per head (block-wide) ----
    float content = 0.f;
    #pragma unroll
    for (int h = 0; h < 5; ++h) {
        float sharp = (dot[h] / (sknorm[h] * mnorm + EPS)) * sscale[h];
        float mx = block_reduce<true>(sharp, sred);
        float e = expf(sharp - mx);
        float sm = block_reduce<false>(e, sred);
        float p = e / sm;
        if (h < R) out_rw[((size_t)b * R + h) * N + t] = p;
        else       content = p;
    }

    // ---- final write weights + precedence ----
    float ag = alloc_gate[b], wg = write_gate[b];
    float w = wg * (ag * salloc[t] + (1.f - ag) * content);
    float wsum = block_reduce<false>(w, sred);
    out_ww[(size_t)b * N + t] = w;
    out_prec[(size_t)b * N + t] = (1.f - wsum) * prev_prec[(size_t)b * N + t] + w;
}

// ---- link update: the HBM-bound bulk. 8 rows per 256-thread block. ----
__global__ __launch_bounds__(256) void k_link(const float* __restrict__ ww,
                                              const float* __restrict__ pprec,
                                              const float* __restrict__ plink,
                                              float* __restrict__ link) {
    int base_row = blockIdx.x * RPB;        // 1024 % RPB == 0 -> same batch
    int b = base_row >> 10;
    int t = threadIdx.x;                    // j-chunk: j in [4t, 4t+4)

    f4 wj = ((const f4*)(ww + (size_t)b * N))[t];
    f4 pj = ((const f4*)(pprec + (size_t)b * N))[t];

    float wis[RPB];
    #pragma unroll
    for (int r = 0; r < RPB; ++r) wis[r] = ww[base_row + r];

    f4 pl[RPB];
    #pragma unroll
    for (int r = 0; r < RPB; ++r)
        pl[r] = __builtin_nontemporal_load(
            (const f4*)plink + (((size_t)(base_row + r)) << 8) + t);

    #pragma unroll
    for (int r = 0; r < RPB; ++r) {
        int i = (base_row + r) & (N - 1);
        float wi = wis[r];
        f4 a = (1.f - wi) - wj;
        f4 o = a * pl[r] + wi * pj;
        if ((i >> 2) == t) {               // zero diagonal element
            int jj = i & 3;
            if      (jj == 0) o.x = 0.f;
            else if (jj == 1) o.y = 0.f;
            else if (jj == 2) o.z = 0.f;
            else              o.w = 0.f;
        }
        __builtin_nontemporal_store(
            o, (f4*)link + (((size_t)(base_row + r)) << 8) + t);
    }
}

extern "C" void kernel_launch(void* const* d_in, const int* in_sizes, int n_in,
                              void* d_out, int out_size, void* d_ws, size_t ws_size,
                              hipStream_t stream) {
    const float* memory          = (const float*)d_in[0];
    const float* read_keys       = (const float*)d_in[1];
    const float* read_strengths  = (const float*)d_in[2];
    const float* write_keys      = (const float*)d_in[3];
    const float* write_strengths = (const float*)d_in[4];
    const float* free_gate       = (const float*)d_in[5];
    const float* alloc_gate      = (const float*)d_in[6];
    const float* write_gate      = (const float*)d_in[7];
    const float* prev_read_w     = (const float*)d_in[8];
    const float* prev_write_w    = (const float*)d_in[9];
    const float* prev_usage      = (const float*)d_in[10];
    const float* prev_link       = (const float*)d_in[11];
    const float* prev_prec       = (const float*)d_in[12];

    float* out = (float*)d_out;
    float* out_rw    = out;                               // [B,R,N]
    float* out_ww    = out_rw + (size_t)B * R * N;        // [B,NW,N]
    float* out_usage = out_ww + (size_t)B * NW * N;       // [B,N]
    float* out_link  = out_usage + (size_t)B * N;         // [B,NW,N,N]
    float* out_prec  = out_link + (size_t)B * NW * N * N; // [B,NW,N]

    k_small<<<B, 1024, 0, stream>>>(memory, read_keys, read_strengths,
                                    write_keys, write_strengths, free_gate,
                                    alloc_gate, write_gate, prev_read_w,
                                    prev_write_w, prev_usage, prev_prec,
                                    out_rw, out_ww, out_usage, out_prec);

    k_link<<<(B * N) / RPB, 256, 0, stream>>>(out_ww, prev_prec, prev_link, out_link);
}

// Round 3
// 172.900 us; speedup vs baseline: 1.0020x; 1.0020x over previous
//
#include <hip/hip_runtime.h>
#include <math.h>

#define EPS 1e-5f
#define B 64
#define N 1024
#define W 64
#define R 4
#define NW 1

typedef float f4 __attribute__((ext_vector_type(4)));

__device__ __forceinline__ float softplus_f(float x) {
    return x > 0.f ? x + log1pf(expf(-x)) : log1pf(expf(x));
}

// -------------------- usage --------------------
__global__ void k_usage(const float* __restrict__ pww,
                        const float* __restrict__ fg,
                        const float* __restrict__ prw,
                        const float* __restrict__ pu,
                        float* __restrict__ usage) {
    int idx = blockIdx.x * blockDim.x + threadIdx.x;  // over B*N
    if (idx >= B * N) return;
    int b = idx >> 10;
    int n = idx & (N - 1);
    float ww = pww[(size_t)b * N + n];          // NW == 1
    float pun = pu[idx];
    float u = pun + (1.f - pun) * ww;
    float phi = 1.f;
    #pragma unroll
    for (int r = 0; r < R; ++r)
        phi *= 1.f - fg[b * R + r] * prw[((size_t)b * R + r) * N + n];
    usage[idx] = u * phi;
}

// ---- allocation WITHOUT sorting: rank-product. grid (4, B) x 256 ----
// alloc_i = (1-uu_i) * prod_{j "before" i in sort order} uu_j,
// where j before i  <=>  uu_j < uu_i  ||  (uu_j == uu_i && j < i)
__global__ __launch_bounds__(256) void k_alloc(const float* __restrict__ usage,
                                               float* __restrict__ alloc) {
    __shared__ float su[N];
    int b = blockIdx.y;
    int t = threadIdx.x;

    f4 uv = ((const f4*)(usage + (size_t)b * N))[t];
    su[4 * t + 0] = EPS + (1.f - EPS) * uv.x;
    su[4 * t + 1] = EPS + (1.f - EPS) * uv.y;
    su[4 * t + 2] = EPS + (1.f - EPS) * uv.z;
    su[4 * t + 3] = EPS + (1.f - EPS) * uv.w;
    __syncthreads();

    int i = blockIdx.x * 256 + t;
    float ui = su[i];
    float prod = 1.f;
    for (int j4 = 0; j4 < N / 4; ++j4) {
        f4 v = ((const f4*)su)[j4];   // uniform addr -> LDS broadcast
        int j = 4 * j4;
        prod *= ((v.x < ui) || (v.x == ui && (j + 0) < i)) ? v.x : 1.f;
        prod *= ((v.y < ui) || (v.y == ui && (j + 1) < i)) ? v.y : 1.f;
        prod *= ((v.z < ui) || (v.z == ui && (j + 2) < i)) ? v.z : 1.f;
        prod *= ((v.w < ui) || (v.w == ui && (j + 3) < i)) ? v.w : 1.f;
    }
    alloc[(size_t)b * N + i] = (1.f - ui) * prod;
}

// -------------------- cosine scores (all 5 heads, one memory pass) ------
__global__ void k_scores(const float* __restrict__ memory,
                         const float* __restrict__ read_keys,
                         const float* __restrict__ read_strengths,
                         const float* __restrict__ write_keys,
                         const float* __restrict__ write_strengths,
                         float* __restrict__ out_rw,   // [B,R,N] sharpened acts
                         float* __restrict__ out_ww) { // [B,N] sharpened acts
    __shared__ float sk[5 * W];
    __shared__ float s_knorm[5];
    __shared__ float s_scale[5];
    int b = blockIdx.y;
    int t = threadIdx.x;   // 256

    for (int l = t; l < 5 * W; l += 256) {
        int h = l / W, w = l - h * W;
        sk[l] = (h < R) ? read_keys[((size_t)b * R + h) * W + w]
                        : write_keys[(size_t)b * W + w];
    }
    __syncthreads();
    if (t < 5) {
        float s = 0.f;
        for (int w = 0; w < W; ++w) s += sk[t * W + w] * sk[t * W + w];
        s_knorm[t] = sqrtf(s + EPS);
        float st = (t < R) ? read_strengths[b * R + t] : write_strengths[b];
        s_scale[t] = softplus_f(st);
    }
    __syncthreads();

    int n = blockIdx.x * 256 + t;
    const f4* mrow = (const f4*)(memory + ((size_t)b * N + n) * W);
    float dot[5] = {0.f, 0.f, 0.f, 0.f, 0.f};
    float msum = 0.f;
    #pragma unroll
    for (int w4 = 0; w4 < W / 4; ++w4) {
        f4 m = mrow[w4];
        msum += m.x * m.x + m.y * m.y + m.z * m.z + m.w * m.w;
        #pragma unroll
        for (int h = 0; h < 5; ++h)
            dot[h] += sk[h * W + w4 * 4 + 0] * m.x + sk[h * W + w4 * 4 + 1] * m.y
                    + sk[h * W + w4 * 4 + 2] * m.z + sk[h * W + w4 * 4 + 3] * m.w;
    }
    float mnorm = sqrtf(msum + EPS);
    #pragma unroll
    for (int h = 0; h < 5; ++h) {
        float sharp = (dot[h] / (s_knorm[h] * mnorm + EPS)) * s_scale[h];
        if (h < R) out_rw[((size_t)b * R + h) * N + n] = sharp;
        else       out_ww[(size_t)b * N + n] = sharp;
    }
}

// ---- softmax over N; write-head block also does ww + precedence ----
__global__ void k_softmax_ww(float* __restrict__ out_rw,
                             float* __restrict__ out_ww,
                             const float* __restrict__ alloc,
                             const float* __restrict__ alloc_gate,
                             const float* __restrict__ write_gate,
                             const float* __restrict__ prev_prec,
                             float* __restrict__ out_prec) {
    int blk = blockIdx.x;     // B*5
    int b = blk / 5, h = blk - b * 5;
    float* p = (h < R) ? (out_rw + ((size_t)b * R + h) * N)
                       : (out_ww + (size_t)b * N);
    int t = threadIdx.x;      // 256
    float v[4];
    float mx = -INFINITY;
    #pragma unroll
    for (int k = 0; k < 4; ++k) { v[k] = p[t + 256 * k]; mx = fmaxf(mx, v[k]); }
    __shared__ float red[256];
    red[t] = mx; __syncthreads();
    for (int s = 128; s > 0; s >>= 1) {
        if (t < s) red[t] = fmaxf(red[t], red[t + s]);
        __syncthreads();
    }
    mx = red[0]; __syncthreads();
    float sum = 0.f;
    #pragma unroll
    for (int k = 0; k < 4; ++k) { v[k] = expf(v[k] - mx); sum += v[k]; }
    red[t] = sum; __syncthreads();
    for (int s = 128; s > 0; s >>= 1) {
        if (t < s) red[t] += red[t + s];
        __syncthreads();
    }
    float inv = 1.f / red[0];
    #pragma unroll
    for (int k = 0; k < 4; ++k) v[k] *= inv;

    if (h < R) {
        #pragma unroll
        for (int k = 0; k < 4; ++k) p[t + 256 * k] = v[k];
        return;
    }

    // write head: final write weights + precedence
    float ag = alloc_gate[b], wg = write_gate[b];
    float w[4];
    float wsum = 0.f;
    #pragma unroll
    for (int k = 0; k < 4; ++k) {
        int n = t + 256 * k;
        w[k] = wg * (ag * alloc[(size_t)b * N + n] + (1.f - ag) * v[k]);
        wsum += w[k];
    }
    __syncthreads();
    red[t] = wsum; __syncthreads();
    for (int s = 128; s > 0; s >>= 1) {
        if (t < s) red[t] += red[t + s];
        __syncthreads();
    }
    wsum = red[0];
    #pragma unroll
    for (int k = 0; k < 4; ++k) {
        int n = t + 256 * k;
        out_ww[(size_t)b * N + n] = w[k];
        out_prec[(size_t)b * N + n] =
            (1.f - wsum) * prev_prec[(size_t)b * N + n] + w[k];
    }
}

// ---- link update (R1-proven form: one row per 256-thread block) ----
__global__ void k_link(const float* __restrict__ ww,
                       const float* __restrict__ pprec,
                       const float* __restrict__ plink,
                       float* __restrict__ link) {
    int row = blockIdx.x;               // b*N + i
    int b = row >> 10, i = row & (N - 1);
    int t = threadIdx.x;                // 256 threads = 256 float4 = one row
    float wi = ww[row];
    size_t base4 = ((size_t)row << 10) >> 2;
    f4 pl = ((const f4*)plink)[base4 + t];
    f4 wj = ((const f4*)(ww + (size_t)b * N))[t];
    f4 pj = ((const f4*)(pprec + (size_t)b * N))[t];
    f4 o;
    o.x = (1.f - wi - wj.x) * pl.x + wi * pj.x;
    o.y = (1.f - wi - wj.y) * pl.y + wi * pj.y;
    o.z = (1.f - wi - wj.z) * pl.z + wi * pj.z;
    o.w = (1.f - wi - wj.w) * pl.w + wi * pj.w;
    int j0 = t * 4;
    if (i >= j0 && i < j0 + 4) {
        if      (i == j0)     o.x = 0.f;
        else if (i == j0 + 1) o.y = 0.f;
        else if (i == j0 + 2) o.z = 0.f;
        else                  o.w = 0.f;
    }
    ((f4*)link)[base4 + t] = o;
}

extern "C" void kernel_launch(void* const* d_in, const int* in_sizes, int n_in,
                              void* d_out, int out_size, void* d_ws, size_t ws_size,
                              hipStream_t stream) {
    const float* memory          = (const float*)d_in[0];
    const float* read_keys       = (const float*)d_in[1];
    const float* read_strengths  = (const float*)d_in[2];
    const float* write_keys      = (const float*)d_in[3];
    const float* write_strengths = (const float*)d_in[4];
    const float* free_gate       = (const float*)d_in[5];
    const float* alloc_gate     = (const float*)d_in[6];
    const float* write_gate      = (const float*)d_in[7];
    const float* prev_read_w     = (const float*)d_in[8];
    const float* prev_write_w    = (const float*)d_in[9];
    const float* prev_usage      = (const float*)d_in[10];
    const float* prev_link       = (const float*)d_in[11];
    const float* prev_prec       = (const float*)d_in[12];

    float* out = (float*)d_out;
    float* out_rw    = out;                               // [B,R,N]
    float* out_ww    = out_rw + (size_t)B * R * N;        // [B,NW,N]
    float* out_usage = out_ww + (size_t)B * NW * N;       // [B,N]
    float* out_link  = out_usage + (size_t)B * N;         // [B,NW,N,N]
    float* out_prec  = out_link + (size_t)B * NW * N * N; // [B,NW,N]

    // alloc scratch lives in the first B*N floats of out_link; k_link fully
    // overwrites that region afterwards, so this is race-free & deterministic.
    float* alloc_buf = out_link;

    k_usage<<<(B * N) / 256, 256, 0, stream>>>(
        prev_write_w, free_gate, prev_read_w, prev_usage, out_usage);

    dim3 ga(N / 256, B);
    k_alloc<<<ga, 256, 0, stream>>>(out_usage, alloc_buf);

    dim3 gs(N / 256, B);
    k_scores<<<gs, 256, 0, stream>>>(memory, read_keys, read_strengths,
                                     write_keys, write_strengths, out_rw, out_ww);

    k_softmax_ww<<<B * 5, 256, 0, stream>>>(out_rw, out_ww, alloc_buf,
                                            alloc_gate, write_gate,
                                            prev_prec, out_prec);

    k_link<<<B * N, 256, 0, stream>>>(out_ww, prev_prec, prev_link, out_link);
}